// Round 3
// baseline (180.472 us; speedup 1.0000x reference)
//
#include <hip/hip_runtime.h>
#include <hip/hip_bf16.h>
#include <cstdint>

// HSTU fused block on MI355X.
//   k0: convert x,W1,W2 fp32->bf16
//   k1: h = silu(x@W1^T+b1) -> gate/q/k into h[8192][2048] (q pre-scaled 0.125), v -> Vt[b,h,d,t]
//       V columns stored PERMUTED within each 32-t chunk (pos quad*8+j <-> t=(j>>2)*16+quad*4+(j&3))
//       so attn's PV A-fragment is lane-local (P stays in registers, no Ps LDS buffer).
//   k2: causal silu-attention (Q-tile 64, K-tile 128). 128-thread blocks: 2 waves, each wave
//       owns 32 q-rows (2x16 fragments) -> every K/V LDS read feeds 2 MFMAs (2x less LDS-read
//       traffic than 4-wave). 40KB LDS -> 4 blocks/CU, all 1024 blocks co-resident; qi mapping
//       statically balances nk-sum to 34 per stride-256 block group.
//   k3: y = (layernorm(o)*g+b) * gate  (bf16)
//   k4: out = y@W2^T + b2 (fp32)
// All MFMA staging tiles use XOR swizzle: LDS chunk c of row r holds global chunk c^(r&7)
// (gl_lds16 writes lane*16B at fixed LDS offset; we permute the *global* source per lane).

typedef __attribute__((ext_vector_type(8))) short short8;
typedef __attribute__((ext_vector_type(4))) float f32x4;

__device__ __forceinline__ unsigned short f2bf(float f) {
  union { float f; unsigned u; } v; v.f = f;
  unsigned r = v.u + 0x7FFFu + ((v.u >> 16) & 1u);
  return (unsigned short)(r >> 16);
}
__device__ __forceinline__ float bf2f(unsigned short h) {
  union { unsigned u; float f; } v; v.u = ((unsigned)h) << 16; return v.f;
}
__device__ __forceinline__ float fast_rcp(float x) {
#if __has_builtin(__builtin_amdgcn_rcpf)
  return __builtin_amdgcn_rcpf(x);
#else
  return 1.0f / x;
#endif
}
__device__ __forceinline__ float fast_exp2(float x) {
#if __has_builtin(__builtin_amdgcn_exp2f)
  return __builtin_amdgcn_exp2f(x);
#else
  return exp2f(x);
#endif
}
// silu without the IEEE-div sequence: x * rcp(1 + 2^(-x*log2e))
__device__ __forceinline__ float silu_f(float x) {
  return x * fast_rcp(1.0f + fast_exp2(-1.442695041f * x));
}
__device__ __forceinline__ unsigned pk2(float lo, float hi) {
  union { __hip_bfloat162 b; unsigned u; } cv;
  cv.b = __float22bfloat162_rn(make_float2(lo, hi));
  return cv.u;
}
__device__ __forceinline__ void gl_lds16(const void* g, void* l) {
  __builtin_amdgcn_global_load_lds(
      (const __attribute__((address_space(1))) void*)g,
      (__attribute__((address_space(3))) void*)l, 16, 0, 0);
}

// ---------------- k0: fp32 -> bf16 convert ----------------
__global__ void convert_kernel(const float* __restrict__ x, const float* __restrict__ w1,
                               const float* __restrict__ w2,
                               unsigned short* __restrict__ xb, unsigned short* __restrict__ w1b,
                               unsigned short* __restrict__ w2b) {
  int i = blockIdx.x * 256 + threadIdx.x;  // one float4 per thread
  const float* s; unsigned short* d;
  if (i < 1048576) { s = x; d = xb; }
  else if (i < 1048576 + 262144) { i -= 1048576; s = w1; d = w1b; }
  else { i -= (1048576 + 262144); if (i >= 65536) return; s = w2; d = w2b; }
  float4 f = ((const float4*)s)[i];
  uint2 o; o.x = pk2(f.x, f.y); o.y = pk2(f.z, f.w);
  ((uint2*)d)[i] = o;
}

// ---------------- k1: GEMM1 + bias + silu -> h (gate/q/k) and vt (v transposed) ----------------
__global__ __launch_bounds__(256, 2) void gemm1_kernel(
    const unsigned short* __restrict__ xb,   // [8192][512]
    const unsigned short* __restrict__ w1b,  // [2048][512]
    const float* __restrict__ b1,            // [2048]
    unsigned short* __restrict__ h,          // [8192][2048] (cols 1536+ unused)
    unsigned short* __restrict__ vt)         // [32*64][2048]  ((b*8+hh)*64+d, pos)
{
  __shared__ __align__(16) unsigned short smem[16896];  // As|Bs (16384) then T[128][132]
  unsigned short* As = smem;          // [128][64] swizzled
  unsigned short* Bs = smem + 8192;
  const int tid = threadIdx.x;
  const int w = tid >> 6, l = tid & 63;
  const int bm = blockIdx.x & 63, bn = blockIdx.x >> 6;
  const int wm = w & 1, wn = w >> 1;
  const int quad = l >> 4, lc = l & 15, lc7 = lc & 7;
  const int r8 = l >> 3, c8 = (l & 7) ^ r8;  // swizzled global chunk

  f32x4 acc[4][4] = {};
  const unsigned short* ga = xb + (size_t)(bm * 128 + w * 32 + r8) * 512 + c8 * 8;
  const unsigned short* gb = w1b + (size_t)(bn * 128 + w * 32 + r8) * 512 + c8 * 8;

  for (int kt = 0; kt < 512; kt += 64) {
#pragma unroll
    for (int i = 0; i < 4; ++i) {
      gl_lds16(ga + i * 8 * 512 + kt, As + (w * 4 + i) * 512);
      gl_lds16(gb + i * 8 * 512 + kt, Bs + (w * 4 + i) * 512);
    }
    __syncthreads();
#pragma unroll
    for (int kk = 0; kk < 2; ++kk) {
      short8 af[4], bf[4];
#pragma unroll
      for (int mt = 0; mt < 4; ++mt)
        af[mt] = *(const short8*)(As + (wm * 64 + mt * 16 + lc) * 64 +
                                  (((kk * 4 + quad) ^ lc7) * 8));
#pragma unroll
      for (int nt = 0; nt < 4; ++nt)
        bf[nt] = *(const short8*)(Bs + (wn * 64 + nt * 16 + lc) * 64 +
                                  (((kk * 4 + quad) ^ lc7) * 8));
#pragma unroll
      for (int mt = 0; mt < 4; ++mt)
#pragma unroll
        for (int nt = 0; nt < 4; ++nt)
          acc[mt][nt] = __builtin_amdgcn_mfma_f32_16x16x32_bf16(af[mt], bf[nt], acc[mt][nt], 0, 0, 0);
    }
    __syncthreads();
  }

  // epilogue: repack C-tile through LDS T, then 256B-coalesced global stores
  unsigned short* T = smem;  // [128][132]
  const int sec = bn >> 2;   // 0 gate, 1 q, 2 k, 3 v (uniform per block)
  if (sec == 3) {
    // T[d_local][s_local]: regs hold 4 consecutive s at fixed n=d -> b64 LDS writes
#pragma unroll
    for (int nt = 0; nt < 4; ++nt) {
      const int nl = wn * 64 + nt * 16 + lc;
      const float bias = b1[bn * 128 + nl];
#pragma unroll
      for (int mt = 0; mt < 4; ++mt) {
        const int sl = wm * 64 + mt * 16 + quad * 4;
        uint2 pk;
        pk.x = pk2(silu_f(acc[mt][nt][0] + bias), silu_f(acc[mt][nt][1] + bias));
        pk.y = pk2(silu_f(acc[mt][nt][2] + bias), silu_f(acc[mt][nt][3] + bias));
        *(uint2*)(T + nl * 132 + sl) = pk;
      }
    }
  } else {
    const float osc = (sec == 1) ? 0.125f : 1.0f;  // fold attention scale into q
#pragma unroll
    for (int nt = 0; nt < 4; ++nt) {
      const int nl = wn * 64 + nt * 16 + lc;
      const float bias = b1[bn * 128 + nl];
#pragma unroll
      for (int mt = 0; mt < 4; ++mt) {
        const int sl = wm * 64 + mt * 16 + quad * 4;
#pragma unroll
        for (int r = 0; r < 4; ++r)
          T[(sl + r) * 132 + nl] = f2bf(silu_f(acc[mt][nt][r] + bias) * osc);
      }
    }
  }
  __syncthreads();
  const int rrow = tid >> 4, rcol = (tid & 15) * 8;
  if (sec == 3) {
    // store V with per-32-chunk position permutation: pos quad*8+j <-> t=(j>>2)*16+quad*4+(j&3)
    const int bq = bm >> 4, sbase = (bm & 15) * 128;
    const int lcq = tid & 15;
    const int t0 = ((lcq >> 2) * 32) + ((lcq & 3) * 4);  // ksl*32 + quad*4
#pragma unroll
    for (int p = 0; p < 8; ++p) {
      const int row = p * 16 + rrow;
      const int n = bn * 128 + row, hh = (n >> 6) & 7, d = n & 63;
      uint2 a = *(const uint2*)(T + row * 132 + t0);
      uint2 bb = *(const uint2*)(T + row * 132 + t0 + 16);
      uint4 st; st.x = a.x; st.y = a.y; st.z = bb.x; st.w = bb.y;
      *(uint4*)(vt + (size_t)((bq * 8 + hh) * 64 + d) * 2048 + sbase + rcol) = st;
    }
  } else {
#pragma unroll
    for (int p = 0; p < 8; ++p) {
      const int row = p * 16 + rrow;
      *(short8*)(h + (size_t)(bm * 128 + row) * 2048 + bn * 128 + rcol) =
          *(const short8*)(T + row * 132 + rcol);
    }
  }
}

// ---------------- k2: causal silu-attention (Q-tile 64, K-tile 128, 2 waves) ----------------
// Wave w owns q rows [w*32, w*32+32) as two 16-row fragments; each kf/vf LDS read feeds both.
__global__ __launch_bounds__(128, 2) void attn_kernel(
    const unsigned short* __restrict__ h,   // q @ +512 (pre-scaled), k @ +1024
    const unsigned short* __restrict__ vt,  // [32*64][2048] position-permuted
    float* __restrict__ o)                  // [8192][512]
{
  __shared__ __align__(16) unsigned short Qs[64 * 64];   // 8KB
  __shared__ __align__(16) unsigned short Ks[128 * 64];  // 16KB swizzled
  __shared__ __align__(16) unsigned short Vs[64 * 128];  // 16KB [d][pos] swizzled
  const int tid = threadIdx.x;
  const int w = tid >> 6, l = tid & 63;  // w in {0,1}
  // static balanced qi partition: stride-256 block groups {g=0..3} get qi {2t,2t+1,30-2t,31-2t}
  // -> nk-sum = 34 for every group (assuming round-robin block->CU assignment).
  const int r256 = blockIdx.x & 255, g = blockIdx.x >> 8;
  const int bh = r256 & 31, tsel = r256 >> 5;  // bh&7 fixed per XCD lane -> K/V L2 locality
  const int qi = (g == 0) ? 2 * tsel
               : (g == 1) ? 2 * tsel + 1
               : (g == 2) ? 30 - 2 * tsel
                          : 31 - 2 * tsel;
  const int b = bh >> 3, hh = bh & 7;
  const int quad = l >> 4, lc = l & 15, lc7 = lc & 7;
  const int r8 = l >> 3, c8 = (l & 7) ^ r8;
  const int q0 = qi * 64;
  const int nk = (qi >> 1) + 1;

  // stage Q [64][64] into Qs (swizzled): wave w rows w*32 + i*8 + r8
  {
    const unsigned short* qg =
        h + (size_t)(b * 2048 + q0 + w * 32 + r8) * 2048 + 512 + hh * 64 + c8 * 8;
#pragma unroll
    for (int i = 0; i < 4; ++i)
      gl_lds16(qg + (size_t)i * 8 * 2048, Qs + (w * 4 + i) * 512);
  }
  __syncthreads();
  short8 qf[2][2];
#pragma unroll
  for (int s = 0; s < 2; ++s)
#pragma unroll
    for (int kk = 0; kk < 2; ++kk)
      qf[s][kk] = *(const short8*)(Qs + (w * 32 + s * 16 + lc) * 64 +
                                   (((kk * 4 + quad) ^ lc7) * 8));

  f32x4 oacc[2][4] = {};

  const unsigned short* kg =
      h + (size_t)(b * 2048 + w * 64 + r8) * 2048 + 1024 + hh * 64 + c8 * 8;
  const int vrow = l >> 4, vcol = l & 15;
  const unsigned short* vgE =
      vt + (size_t)(bh * 64 + w * 32 + vrow) * 2048 + ((vcol ^ vrow) * 8);
  const unsigned short* vgO =
      vt + (size_t)(bh * 64 + w * 32 + vrow) * 2048 + ((vcol ^ vrow ^ 4) * 8);

  for (int ti = 0; ti < nk; ++ti) {
    __syncthreads();  // prev readers done (ti=0: qf reads done)
    const int toff = ti * 128;
    // stage K rows w*64+i*8+r8 and V rows w*32+i*4+vrow, i=0..7
#pragma unroll
    for (int i = 0; i < 8; ++i) {
      gl_lds16(kg + (size_t)(toff + i * 8) * 2048, Ks + (w * 8 + i) * 512);
      const unsigned short* vsrc = ((i & 1) ? vgO : vgE) + (size_t)(i * 4) * 2048 + toff;
      gl_lds16(vsrc, Vs + (w * 8 + i) * 512);
    }
    __syncthreads();

    // Sc^T = K Q^T : lane holds C[t = mt*16 + quad*4 + r][q = w*32 + s*16 + lc]
    f32x4 sc[2][8] = {};
#pragma unroll
    for (int kk = 0; kk < 2; ++kk)
#pragma unroll
      for (int mt = 0; mt < 8; ++mt) {
        short8 kf = *(const short8*)(Ks + (mt * 16 + lc) * 64 +
                                     (((kk * 4 + quad) ^ lc7) * 8));
        sc[0][mt] = __builtin_amdgcn_mfma_f32_16x16x32_bf16(kf, qf[0][kk], sc[0][mt], 0, 0, 0);
        sc[1][mt] = __builtin_amdgcn_mfma_f32_16x16x32_bf16(kf, qf[1][kk], sc[1][mt], 0, 0, 0);
      }

    // silu (+causal mask on diagonal tile) in-register, then PV.
    // PV A-frag position quad*8+j <-> t = ks*32 + (j>>2)*16 + quad*4 + (j&3)
    // == lane's own sc[s][2ks + (j>>2)][j&3]; V stored position-permuted to match.
    if (ti < nk - 1) {
#pragma unroll
      for (int ks = 0; ks < 4; ++ks) {
        union { short8 s; unsigned u[4]; } pf0, pf1;
        pf0.u[0] = pk2(silu_f(sc[0][2 * ks][0]), silu_f(sc[0][2 * ks][1]));
        pf0.u[1] = pk2(silu_f(sc[0][2 * ks][2]), silu_f(sc[0][2 * ks][3]));
        pf0.u[2] = pk2(silu_f(sc[0][2 * ks + 1][0]), silu_f(sc[0][2 * ks + 1][1]));
        pf0.u[3] = pk2(silu_f(sc[0][2 * ks + 1][2]), silu_f(sc[0][2 * ks + 1][3]));
        pf1.u[0] = pk2(silu_f(sc[1][2 * ks][0]), silu_f(sc[1][2 * ks][1]));
        pf1.u[1] = pk2(silu_f(sc[1][2 * ks][2]), silu_f(sc[1][2 * ks][3]));
        pf1.u[2] = pk2(silu_f(sc[1][2 * ks + 1][0]), silu_f(sc[1][2 * ks + 1][1]));
        pf1.u[3] = pk2(silu_f(sc[1][2 * ks + 1][2]), silu_f(sc[1][2 * ks + 1][3]));
#pragma unroll
        for (int nt = 0; nt < 4; ++nt) {
          short8 vf = *(const short8*)(Vs + (nt * 16 + lc) * 128 +
                                       (((ks * 4 + quad) ^ lc7) * 8));
          oacc[0][nt] = __builtin_amdgcn_mfma_f32_16x16x32_bf16(pf0.s, vf, oacc[0][nt], 0, 0, 0);
          oacc[1][nt] = __builtin_amdgcn_mfma_f32_16x16x32_bf16(pf1.s, vf, oacc[1][nt], 0, 0, 0);
        }
      }
    } else {
      const int qrow0 = q0 + w * 32 + lc;        // slice 0
      const int qrow1 = qrow0 + 16;              // slice 1
#pragma unroll
      for (int ks = 0; ks < 4; ++ks) {
        float v0[8], v1[8];
#pragma unroll
        for (int gg = 0; gg < 2; ++gg) {
          const int tb = toff + (2 * ks + gg) * 16 + quad * 4;
#pragma unroll
          for (int r = 0; r < 4; ++r) {
            float s0 = silu_f(sc[0][2 * ks + gg][r]);
            float s1 = silu_f(sc[1][2 * ks + gg][r]);
            v0[gg * 4 + r] = (tb + r <= qrow0) ? s0 : 0.0f;
            v1[gg * 4 + r] = (tb + r <= qrow1) ? s1 : 0.0f;
          }
        }
        union { short8 s; unsigned u[4]; } pf0, pf1;
        pf0.u[0] = pk2(v0[0], v0[1]); pf0.u[1] = pk2(v0[2], v0[3]);
        pf0.u[2] = pk2(v0[4], v0[5]); pf0.u[3] = pk2(v0[6], v0[7]);
        pf1.u[0] = pk2(v1[0], v1[1]); pf1.u[1] = pk2(v1[2], v1[3]);
        pf1.u[2] = pk2(v1[4], v1[5]); pf1.u[3] = pk2(v1[6], v1[7]);
#pragma unroll
        for (int nt = 0; nt < 4; ++nt) {
          short8 vf = *(const short8*)(Vs + (nt * 16 + lc) * 128 +
                                       (((ks * 4 + quad) ^ lc7) * 8));
          oacc[0][nt] = __builtin_amdgcn_mfma_f32_16x16x32_bf16(pf0.s, vf, oacc[0][nt], 0, 0, 0);
          oacc[1][nt] = __builtin_amdgcn_mfma_f32_16x16x32_bf16(pf1.s, vf, oacc[1][nt], 0, 0, 0);
        }
      }
    }
  }

#pragma unroll
  for (int s = 0; s < 2; ++s) {
    float* og = o + (size_t)(b * 2048 + q0 + w * 32 + s * 16) * 512 + hh * 64;
#pragma unroll
    for (int nt = 0; nt < 4; ++nt)
#pragma unroll
      for (int r = 0; r < 4; ++r)
        og[(quad * 4 + r) * 512 + nt * 16 + lc] = oacc[s][nt][r];
  }
}

// ---------------- k3: layernorm * gate -> y (bf16) ----------------
__global__ __launch_bounds__(256) void ln_gate_kernel(
    const float* __restrict__ o, const unsigned short* __restrict__ h,
    const float* __restrict__ lng, const float* __restrict__ lnb,
    unsigned short* __restrict__ y) {
  const int row = blockIdx.x * 4 + (threadIdx.x >> 6);
  const int l = threadIdx.x & 63;
  const float4* orow = (const float4*)(o + (size_t)row * 512);
  float4 a = orow[l * 2], c = orow[l * 2 + 1];
  float s0 = a.x + a.y + a.z + a.w + c.x + c.y + c.z + c.w;
#pragma unroll
  for (int off = 32; off > 0; off >>= 1) s0 += __shfl_xor(s0, off);
  const float mean = s0 * (1.0f / 512.0f);
  float dx[8] = {a.x - mean, a.y - mean, a.z - mean, a.w - mean,
                 c.x - mean, c.y - mean, c.z - mean, c.w - mean};
  float sq = 0.f;
#pragma unroll
  for (int j = 0; j < 8; ++j) sq += dx[j] * dx[j];
#pragma unroll
  for (int off = 32; off > 0; off >>= 1) sq += __shfl_xor(sq, off);
  const float inv = rsqrtf(sq * (1.0f / 512.0f) + 1e-5f);
  const float4* g4 = (const float4*)lng;
  const float4* b4 = (const float4*)lnb;
  float4 g0 = g4[l * 2], g1 = g4[l * 2 + 1], bb0 = b4[l * 2], bb1 = b4[l * 2 + 1];
  const unsigned short* grow = h + (size_t)row * 2048;  // gate = cols [0,512)
  ushort4 gr0 = *(const ushort4*)(grow + l * 8);
  ushort4 gr1 = *(const ushort4*)(grow + l * 8 + 4);
  float gg[8] = {g0.x, g0.y, g0.z, g0.w, g1.x, g1.y, g1.z, g1.w};
  float bbv[8] = {bb0.x, bb0.y, bb0.z, bb0.w, bb1.x, bb1.y, bb1.z, bb1.w};
  float gv[8] = {bf2f(gr0.x), bf2f(gr0.y), bf2f(gr0.z), bf2f(gr0.w),
                 bf2f(gr1.x), bf2f(gr1.y), bf2f(gr1.z), bf2f(gr1.w)};
  float r[8];
#pragma unroll
  for (int j = 0; j < 8; ++j) r[j] = (dx[j] * inv * gg[j] + bbv[j]) * gv[j];
  uint2 p0, p1;
  p0.x = pk2(r[0], r[1]); p0.y = pk2(r[2], r[3]);
  p1.x = pk2(r[4], r[5]); p1.y = pk2(r[6], r[7]);
  uint2* yrow = (uint2*)(y + (size_t)row * 512);
  yrow[l * 2] = p0;
  yrow[l * 2 + 1] = p1;
}

// ---------------- k4: GEMM2 + bias -> out (fp32) ----------------
__global__ __launch_bounds__(256, 2) void gemm2_kernel(
    const unsigned short* __restrict__ yb,   // [8192][512]
    const unsigned short* __restrict__ w2b,  // [512][512]
    const float* __restrict__ b2, float* __restrict__ out) {
  __shared__ __align__(16) unsigned short As[128 * 64];
  __shared__ __align__(16) unsigned short Bs[128 * 64];
  const int tid = threadIdx.x;
  const int w = tid >> 6, l = tid & 63;
  const int bm = blockIdx.x & 63, bn = blockIdx.x >> 6;
  const int wm = w & 1, wn = w >> 1;
  const int quad = l >> 4, lc = l & 15, lc7 = lc & 7;
  const int r8 = l >> 3, c8 = (l & 7) ^ r8;

  f32x4 acc[4][4] = {};
  const unsigned short* ga = yb + (size_t)(bm * 128 + w * 32 + r8) * 512 + c8 * 8;
  const unsigned short* gb = w2b + (size_t)(bn * 128 + w * 32 + r8) * 512 + c8 * 8;

  for (int kt = 0; kt < 512; kt += 64) {
#pragma unroll
    for (int i = 0; i < 4; ++i) {
      gl_lds16(ga + i * 8 * 512 + kt, As + (w * 4 + i) * 512);
      gl_lds16(gb + i * 8 * 512 + kt, Bs + (w * 4 + i) * 512);
    }
    __syncthreads();
#pragma unroll
    for (int kk = 0; kk < 2; ++kk) {
      short8 af[4], bf[4];
#pragma unroll
      for (int mt = 0; mt < 4; ++mt)
        af[mt] = *(const short8*)(As + (wm * 64 + mt * 16 + lc) * 64 +
                                  (((kk * 4 + quad) ^ lc7) * 8));
#pragma unroll
      for (int nt = 0; nt < 4; ++nt)
        bf[nt] = *(const short8*)(Bs + (wn * 64 + nt * 16 + lc) * 64 +
                                  (((kk * 4 + quad) ^ lc7) * 8));
#pragma unroll
      for (int mt = 0; mt < 4; ++mt)
#pragma unroll
        for (int nt = 0; nt < 4; ++nt)
          acc[mt][nt] = __builtin_amdgcn_mfma_f32_16x16x32_bf16(af[mt], bf[nt], acc[mt][nt], 0, 0, 0);
    }
    __syncthreads();
  }

#pragma unroll
  for (int nt = 0; nt < 4; ++nt) {
    const int n = bn * 128 + wn * 64 + nt * 16 + lc;
    const float bias = b2[n];
#pragma unroll
    for (int mt = 0; mt < 4; ++mt) {
      const int m0 = bm * 128 + wm * 64 + mt * 16 + quad * 4;
#pragma unroll
      for (int r = 0; r < 4; ++r)
        out[(size_t)(m0 + r) * 512 + n] = acc[mt][nt][r] + bias;
    }
  }
}

extern "C" void kernel_launch(void* const* d_in, const int* in_sizes, int n_in,
                              void* d_out, int out_size, void* d_ws, size_t ws_size,
                              hipStream_t stream) {
  const float* x = (const float*)d_in[0];
  const float* W1 = (const float*)d_in[1];
  const float* b1 = (const float*)d_in[2];
  const float* lng = (const float*)d_in[3];
  const float* lnb = (const float*)d_in[4];
  const float* W2 = (const float*)d_in[5];
  const float* b2 = (const float*)d_in[6];
  float* out = (float*)d_out;
  char* ws = (char*)d_ws;

  unsigned short* xb  = (unsigned short*)(ws);
  unsigned short* w1b = (unsigned short*)(ws + 8388608);
  unsigned short* w2b = (unsigned short*)(ws + 10485760);
  unsigned short* h   = (unsigned short*)(ws + 11010048);
  unsigned short* vt  = (unsigned short*)(ws + 44564480);
  float* o            = (float*)(ws + 52953088);
  unsigned short* yb  = (unsigned short*)(ws + 69730304);

  convert_kernel<<<5376, 256, 0, stream>>>(x, W1, W2, xb, w1b, w2b);
  gemm1_kernel<<<1024, 256, 0, stream>>>(xb, w1b, b1, h, vt);
  attn_kernel<<<1024, 128, 0, stream>>>(h, vt, o);
  ln_gate_kernel<<<2048, 256, 0, stream>>>(o, h, lng, lnb, yb);
  gemm2_kernel<<<256, 256, 0, stream>>>(yb, w2b, b2, out);
}

// Round 4
// 173.507 us; speedup vs baseline: 1.0401x; 1.0401x over previous
//
#include <hip/hip_runtime.h>
#include <hip/hip_bf16.h>
#include <cstdint>

// HSTU fused block on MI355X.
//   k0: convert x,W1,W2 fp32->bf16
//   k1: h = silu(x@W1^T+b1) -> gate/q/k into h[8192][2048] (q pre-scaled 0.125), v -> Vt[b,h,d,t]
//       V columns stored PERMUTED within each 32-t chunk (pos quad*8+j <-> t=(j>>2)*16+quad*4+(j&3))
//       so attn's PV A-fragment is lane-local (P stays in registers, no Ps LDS buffer).
//   k2: causal silu-attention (Q-tile 64, K-tile 128, 4 waves, R1 structure). Work split so EVERY
//       block is 8 or 9 tile-units (mapping-independent balance): block=(bh,p,half);
//       A=31-p: half0 = A-tiles[0,8) -> o0; half1 = A-tiles[8,nkA) -> o1(partial) then all of
//       B=p -> o0. ln_gate sums o0+o1 for rows s>=1024. o1 lives in dead xb workspace.
//   k3: y = (layernorm(o0 [+o1])*g+b) * gate  (bf16)
//   k4: out = y@W2^T + b2 (fp32), 128x64 tiles -> 512 blocks (2/CU)
// All MFMA staging tiles use XOR swizzle: LDS chunk c of row r holds global chunk c^(r&7)
// (gl_lds16 writes lane*16B at fixed LDS offset; we permute the *global* source per lane).

typedef __attribute__((ext_vector_type(8))) short short8;
typedef __attribute__((ext_vector_type(4))) float f32x4;

__device__ __forceinline__ unsigned short f2bf(float f) {
  union { float f; unsigned u; } v; v.f = f;
  unsigned r = v.u + 0x7FFFu + ((v.u >> 16) & 1u);
  return (unsigned short)(r >> 16);
}
__device__ __forceinline__ float bf2f(unsigned short h) {
  union { unsigned u; float f; } v; v.u = ((unsigned)h) << 16; return v.f;
}
__device__ __forceinline__ float fast_rcp(float x) {
#if __has_builtin(__builtin_amdgcn_rcpf)
  return __builtin_amdgcn_rcpf(x);
#else
  return 1.0f / x;
#endif
}
__device__ __forceinline__ float fast_exp2(float x) {
#if __has_builtin(__builtin_amdgcn_exp2f)
  return __builtin_amdgcn_exp2f(x);
#else
  return exp2f(x);
#endif
}
// silu without the IEEE-div sequence: x * rcp(1 + 2^(-x*log2e))
__device__ __forceinline__ float silu_f(float x) {
  return x * fast_rcp(1.0f + fast_exp2(-1.442695041f * x));
}
__device__ __forceinline__ unsigned pk2(float lo, float hi) {
  union { __hip_bfloat162 b; unsigned u; } cv;
  cv.b = __float22bfloat162_rn(make_float2(lo, hi));
  return cv.u;
}
__device__ __forceinline__ void gl_lds16(const void* g, void* l) {
  __builtin_amdgcn_global_load_lds(
      (const __attribute__((address_space(1))) void*)g,
      (__attribute__((address_space(3))) void*)l, 16, 0, 0);
}

// ---------------- k0: fp32 -> bf16 convert ----------------
__global__ void convert_kernel(const float* __restrict__ x, const float* __restrict__ w1,
                               const float* __restrict__ w2,
                               unsigned short* __restrict__ xb, unsigned short* __restrict__ w1b,
                               unsigned short* __restrict__ w2b) {
  int i = blockIdx.x * 256 + threadIdx.x;  // one float4 per thread
  const float* s; unsigned short* d;
  if (i < 1048576) { s = x; d = xb; }
  else if (i < 1048576 + 262144) { i -= 1048576; s = w1; d = w1b; }
  else { i -= (1048576 + 262144); if (i >= 65536) return; s = w2; d = w2b; }
  float4 f = ((const float4*)s)[i];
  uint2 o; o.x = pk2(f.x, f.y); o.y = pk2(f.z, f.w);
  ((uint2*)d)[i] = o;
}

// ---------------- k1: GEMM1 + bias + silu -> h (gate/q/k) and vt (v transposed) ----------------
__global__ __launch_bounds__(256, 2) void gemm1_kernel(
    const unsigned short* __restrict__ xb,   // [8192][512]
    const unsigned short* __restrict__ w1b,  // [2048][512]
    const float* __restrict__ b1,            // [2048]
    unsigned short* __restrict__ h,          // [8192][2048] (cols 1536+ unused)
    unsigned short* __restrict__ vt)         // [32*64][2048]  ((b*8+hh)*64+d, pos)
{
  __shared__ __align__(16) unsigned short smem[16896];  // As|Bs (16384) then T[128][132]
  unsigned short* As = smem;          // [128][64] swizzled
  unsigned short* Bs = smem + 8192;
  const int tid = threadIdx.x;
  const int w = tid >> 6, l = tid & 63;
  const int bm = blockIdx.x & 63, bn = blockIdx.x >> 6;
  const int wm = w & 1, wn = w >> 1;
  const int quad = l >> 4, lc = l & 15, lc7 = lc & 7;
  const int r8 = l >> 3, c8 = (l & 7) ^ r8;  // swizzled global chunk

  f32x4 acc[4][4] = {};
  const unsigned short* ga = xb + (size_t)(bm * 128 + w * 32 + r8) * 512 + c8 * 8;
  const unsigned short* gb = w1b + (size_t)(bn * 128 + w * 32 + r8) * 512 + c8 * 8;

  for (int kt = 0; kt < 512; kt += 64) {
#pragma unroll
    for (int i = 0; i < 4; ++i) {
      gl_lds16(ga + i * 8 * 512 + kt, As + (w * 4 + i) * 512);
      gl_lds16(gb + i * 8 * 512 + kt, Bs + (w * 4 + i) * 512);
    }
    __syncthreads();
#pragma unroll
    for (int kk = 0; kk < 2; ++kk) {
      short8 af[4], bf[4];
#pragma unroll
      for (int mt = 0; mt < 4; ++mt)
        af[mt] = *(const short8*)(As + (wm * 64 + mt * 16 + lc) * 64 +
                                  (((kk * 4 + quad) ^ lc7) * 8));
#pragma unroll
      for (int nt = 0; nt < 4; ++nt)
        bf[nt] = *(const short8*)(Bs + (wn * 64 + nt * 16 + lc) * 64 +
                                  (((kk * 4 + quad) ^ lc7) * 8));
#pragma unroll
      for (int mt = 0; mt < 4; ++mt)
#pragma unroll
        for (int nt = 0; nt < 4; ++nt)
          acc[mt][nt] = __builtin_amdgcn_mfma_f32_16x16x32_bf16(af[mt], bf[nt], acc[mt][nt], 0, 0, 0);
    }
    __syncthreads();
  }

  // epilogue: repack C-tile through LDS T, then 256B-coalesced global stores
  unsigned short* T = smem;  // [128][132]
  const int sec = bn >> 2;   // 0 gate, 1 q, 2 k, 3 v (uniform per block)
  if (sec == 3) {
    // T[d_local][s_local]: regs hold 4 consecutive s at fixed n=d -> b64 LDS writes
#pragma unroll
    for (int nt = 0; nt < 4; ++nt) {
      const int nl = wn * 64 + nt * 16 + lc;
      const float bias = b1[bn * 128 + nl];
#pragma unroll
      for (int mt = 0; mt < 4; ++mt) {
        const int sl = wm * 64 + mt * 16 + quad * 4;
        uint2 pk;
        pk.x = pk2(silu_f(acc[mt][nt][0] + bias), silu_f(acc[mt][nt][1] + bias));
        pk.y = pk2(silu_f(acc[mt][nt][2] + bias), silu_f(acc[mt][nt][3] + bias));
        *(uint2*)(T + nl * 132 + sl) = pk;
      }
    }
  } else {
    const float osc = (sec == 1) ? 0.125f : 1.0f;  // fold attention scale into q
#pragma unroll
    for (int nt = 0; nt < 4; ++nt) {
      const int nl = wn * 64 + nt * 16 + lc;
      const float bias = b1[bn * 128 + nl];
#pragma unroll
      for (int mt = 0; mt < 4; ++mt) {
        const int sl = wm * 64 + mt * 16 + quad * 4;
#pragma unroll
        for (int r = 0; r < 4; ++r)
          T[(sl + r) * 132 + nl] = f2bf(silu_f(acc[mt][nt][r] + bias) * osc);
      }
    }
  }
  __syncthreads();
  const int rrow = tid >> 4, rcol = (tid & 15) * 8;
  if (sec == 3) {
    // store V with per-32-chunk position permutation: pos quad*8+j <-> t=(j>>2)*16+quad*4+(j&3)
    const int bq = bm >> 4, sbase = (bm & 15) * 128;
    const int lcq = tid & 15;
    const int t0 = ((lcq >> 2) * 32) + ((lcq & 3) * 4);  // ksl*32 + quad*4
#pragma unroll
    for (int p = 0; p < 8; ++p) {
      const int row = p * 16 + rrow;
      const int n = bn * 128 + row, hh = (n >> 6) & 7, d = n & 63;
      uint2 a = *(const uint2*)(T + row * 132 + t0);
      uint2 bb = *(const uint2*)(T + row * 132 + t0 + 16);
      uint4 st; st.x = a.x; st.y = a.y; st.z = bb.x; st.w = bb.y;
      *(uint4*)(vt + (size_t)((bq * 8 + hh) * 64 + d) * 2048 + sbase + rcol) = st;
    }
  } else {
#pragma unroll
    for (int p = 0; p < 8; ++p) {
      const int row = p * 16 + rrow;
      *(short8*)(h + (size_t)(bm * 128 + row) * 2048 + bn * 128 + rcol) =
          *(const short8*)(T + row * 132 + rcol);
    }
  }
}

// ---------------- k2: causal silu-attention (Q-tile 64, K-tile 128, balanced split) ----------
// block = (bh, p, hf). A = q-tile 31-p (nkA in [9,16]), B = q-tile p (nkB = 17-nkA).
// hf=0: A-tiles [0,8) (8 units, no diagonal) -> o0[A rows].
// hf=1: A-tiles [8,nkA) -> o1[A rows] (partial), then B-tiles [0,nkB) -> o0[B rows]. 9 units.
// Per wave: q rows [w*16, w*16+16), all 128 t. P stays in registers (V position-permuted).
__global__ __launch_bounds__(256, 4) void attn_kernel(
    const unsigned short* __restrict__ h,   // q @ +512 (pre-scaled), k @ +1024
    const unsigned short* __restrict__ vt,  // [32*64][2048] position-permuted
    float* __restrict__ o,                  // o0 [8192][512]
    float* __restrict__ o1)                 // A-rows partial: [(b*1024 + s-1024)][512]
{
  __shared__ __align__(16) unsigned short Ks[128 * 64];  // swizzled; Q staged here too
  __shared__ __align__(16) unsigned short Vs[64 * 128];  // [d][pos] swizzled
  const int tid = threadIdx.x;
  const int w = tid >> 6, l = tid & 63;
  const int bh = blockIdx.x & 31;
  const int job = blockIdx.x >> 5;  // 0..31
  const int p = job >> 1, hf = job & 1;
  const int b = bh >> 3, hh = bh & 7;
  const int quad = l >> 4, lc = l & 15, lc7 = lc & 7;
  const int r8 = l >> 3, c8 = (l & 7) ^ r8;
  const int qiA = 31 - p;
  const int nkA = (qiA >> 1) + 1;  // 9..16

  const unsigned short* kg =
      h + (size_t)(b * 2048 + w * 32 + r8) * 2048 + 1024 + hh * 64 + c8 * 8;
  const int vrow = l >> 4, vcol = l & 15;
  const unsigned short* vgE =
      vt + (size_t)(bh * 64 + w * 16 + vrow) * 2048 + ((vcol ^ vrow) * 8);
  const unsigned short* vgO =
      vt + (size_t)(bh * 64 + w * 16 + vrow) * 2048 + ((vcol ^ vrow ^ 4) * 8);

  short8 qf[2];
  f32x4 oacc[4] = {};

  auto stageQ = [&](int q0) {
    const unsigned short* qg =
        h + (size_t)(b * 2048 + q0 + w * 16 + r8) * 2048 + 512 + hh * 64 + c8 * 8;
#pragma unroll
    for (int i = 0; i < 2; ++i)
      gl_lds16(qg + (size_t)i * 8 * 2048, Ks + (w * 2 + i) * 512);
  };
  auto readQ = [&]() {
#pragma unroll
    for (int kk = 0; kk < 2; ++kk)
      qf[kk] = *(const short8*)(Ks + (w * 16 + lc) * 64 + (((kk * 4 + quad) ^ lc7) * 8));
  };
  auto stageKV = [&](int ti) {
    const int toff = ti * 128;
#pragma unroll
    for (int i = 0; i < 4; ++i) {
      gl_lds16(kg + (size_t)(toff + i * 8) * 2048, Ks + (w * 4 + i) * 512);
      const unsigned short* vsrc = ((i & 1) ? vgO : vgE) + (size_t)(i * 4) * 2048 + toff;
      gl_lds16(vsrc, Vs + (w * 4 + i) * 512);
    }
  };
  auto computeTile = [&](bool dg, int q0, int toff) {
    // Sc^T = K Q^T : lane holds C[t = mt*16 + quad*4 + r][q = w*16 + lc]
    f32x4 sc[8] = {};
#pragma unroll
    for (int kk = 0; kk < 2; ++kk)
#pragma unroll
      for (int mt = 0; mt < 8; ++mt) {
        short8 kf = *(const short8*)(Ks + (mt * 16 + lc) * 64 +
                                     (((kk * 4 + quad) ^ lc7) * 8));
        sc[mt] = __builtin_amdgcn_mfma_f32_16x16x32_bf16(kf, qf[kk], sc[mt], 0, 0, 0);
      }
    // silu (+causal mask on diagonal tile) in-register, then PV.
    // PV A-frag position quad*8+j <-> t = ks*32 + (j>>2)*16 + quad*4 + (j&3)
    // == lane's own sc[2ks + (j>>2)][j&3]; V stored position-permuted to match.
    if (!dg) {
#pragma unroll
      for (int ks = 0; ks < 4; ++ks) {
        union { short8 s; unsigned u[4]; } pf;
        pf.u[0] = pk2(silu_f(sc[2 * ks][0]), silu_f(sc[2 * ks][1]));
        pf.u[1] = pk2(silu_f(sc[2 * ks][2]), silu_f(sc[2 * ks][3]));
        pf.u[2] = pk2(silu_f(sc[2 * ks + 1][0]), silu_f(sc[2 * ks + 1][1]));
        pf.u[3] = pk2(silu_f(sc[2 * ks + 1][2]), silu_f(sc[2 * ks + 1][3]));
#pragma unroll
        for (int nt = 0; nt < 4; ++nt) {
          short8 vf = *(const short8*)(Vs + (nt * 16 + lc) * 128 +
                                       (((ks * 4 + quad) ^ lc7) * 8));
          oacc[nt] = __builtin_amdgcn_mfma_f32_16x16x32_bf16(pf.s, vf, oacc[nt], 0, 0, 0);
        }
      }
    } else {
      const int qrow = q0 + w * 16 + lc;
#pragma unroll
      for (int ks = 0; ks < 4; ++ks) {
        float v[8];
#pragma unroll
        for (int g = 0; g < 2; ++g) {
          const int tb = toff + (2 * ks + g) * 16 + quad * 4;
#pragma unroll
          for (int r = 0; r < 4; ++r) {
            float s = silu_f(sc[2 * ks + g][r]);
            v[g * 4 + r] = (tb + r <= qrow) ? s : 0.0f;
          }
        }
        union { short8 s; unsigned u[4]; } pf;
        pf.u[0] = pk2(v[0], v[1]);
        pf.u[1] = pk2(v[2], v[3]);
        pf.u[2] = pk2(v[4], v[5]);
        pf.u[3] = pk2(v[6], v[7]);
#pragma unroll
        for (int nt = 0; nt < 4; ++nt) {
          short8 vf = *(const short8*)(Vs + (nt * 16 + lc) * 128 +
                                       (((ks * 4 + quad) ^ lc7) * 8));
          oacc[nt] = __builtin_amdgcn_mfma_f32_16x16x32_bf16(pf.s, vf, oacc[nt], 0, 0, 0);
        }
      }
    }
  };
  auto writeO = [&](float* base) {  // base already points at this wave's 16-row block
#pragma unroll
    for (int nt = 0; nt < 4; ++nt)
#pragma unroll
      for (int r = 0; r < 4; ++r)
        base[(quad * 4 + r) * 512 + nt * 16 + lc] = oacc[nt][r];
  };

  if (hf == 0) {
    const int q0 = qiA * 64;
    stageQ(q0);
    __syncthreads();
    readQ();
    for (int ti = 0; ti < 8; ++ti) {
      __syncthreads();
      stageKV(ti);
      __syncthreads();
      computeTile(false, q0, ti * 128);
    }
    writeO(o + (size_t)(b * 2048 + q0 + w * 16) * 512 + hh * 64);
  } else {
    const int q0 = qiA * 64;
    stageQ(q0);
    __syncthreads();
    readQ();
    for (int ti = 8; ti < nkA; ++ti) {
      __syncthreads();
      stageKV(ti);
      __syncthreads();
      computeTile(ti == nkA - 1, q0, ti * 128);
    }
    writeO(o1 + (size_t)(b * 1024 + (q0 - 1024) + w * 16) * 512 + hh * 64);
#pragma unroll
    for (int z = 0; z < 4; ++z) oacc[z] = (f32x4){0.f, 0.f, 0.f, 0.f};
    __syncthreads();  // all waves done reading Ks/Vs before Q restage
    const int q0B = p * 64;
    const int nkB = 17 - nkA;
    stageQ(q0B);
    __syncthreads();
    readQ();
    for (int ti = 0; ti < nkB; ++ti) {
      __syncthreads();
      stageKV(ti);
      __syncthreads();
      computeTile(ti == nkB - 1, q0B, ti * 128);
    }
    writeO(o + (size_t)(b * 2048 + q0B + w * 16) * 512 + hh * 64);
  }
}

// ---------------- k3: layernorm * gate -> y (bf16) ----------------
__global__ __launch_bounds__(256) void ln_gate_kernel(
    const float* __restrict__ o, const float* __restrict__ o1,
    const unsigned short* __restrict__ h,
    const float* __restrict__ lng, const float* __restrict__ lnb,
    unsigned short* __restrict__ y) {
  const int row = blockIdx.x * 4 + (threadIdx.x >> 6);
  const int l = threadIdx.x & 63;
  const float4* orow = (const float4*)(o + (size_t)row * 512);
  float4 a = orow[l * 2], c = orow[l * 2 + 1];
  const int s = row & 2047;
  if (s >= 1024) {  // uniform per wave: add the second partial
    const float4* o1row =
        (const float4*)(o1 + (size_t)((row >> 11) * 1024 + (s - 1024)) * 512);
    float4 a1 = o1row[l * 2], c1 = o1row[l * 2 + 1];
    a.x += a1.x; a.y += a1.y; a.z += a1.z; a.w += a1.w;
    c.x += c1.x; c.y += c1.y; c.z += c1.z; c.w += c1.w;
  }
  float s0 = a.x + a.y + a.z + a.w + c.x + c.y + c.z + c.w;
#pragma unroll
  for (int off = 32; off > 0; off >>= 1) s0 += __shfl_xor(s0, off);
  const float mean = s0 * (1.0f / 512.0f);
  float dx[8] = {a.x - mean, a.y - mean, a.z - mean, a.w - mean,
                 c.x - mean, c.y - mean, c.z - mean, c.w - mean};
  float sq = 0.f;
#pragma unroll
  for (int j = 0; j < 8; ++j) sq += dx[j] * dx[j];
#pragma unroll
  for (int off = 32; off > 0; off >>= 1) sq += __shfl_xor(sq, off);
  const float inv = rsqrtf(sq * (1.0f / 512.0f) + 1e-5f);
  const float4* g4 = (const float4*)lng;
  const float4* b4 = (const float4*)lnb;
  float4 g0 = g4[l * 2], g1 = g4[l * 2 + 1], bb0 = b4[l * 2], bb1 = b4[l * 2 + 1];
  const unsigned short* grow = h + (size_t)row * 2048;  // gate = cols [0,512)
  ushort4 gr0 = *(const ushort4*)(grow + l * 8);
  ushort4 gr1 = *(const ushort4*)(grow + l * 8 + 4);
  float gg[8] = {g0.x, g0.y, g0.z, g0.w, g1.x, g1.y, g1.z, g1.w};
  float bbv[8] = {bb0.x, bb0.y, bb0.z, bb0.w, bb1.x, bb1.y, bb1.z, bb1.w};
  float gv[8] = {bf2f(gr0.x), bf2f(gr0.y), bf2f(gr0.z), bf2f(gr0.w),
                 bf2f(gr1.x), bf2f(gr1.y), bf2f(gr1.z), bf2f(gr1.w)};
  float r[8];
#pragma unroll
  for (int j = 0; j < 8; ++j) r[j] = (dx[j] * inv * gg[j] + bbv[j]) * gv[j];
  uint2 p0, p1;
  p0.x = pk2(r[0], r[1]); p0.y = pk2(r[2], r[3]);
  p1.x = pk2(r[4], r[5]); p1.y = pk2(r[6], r[7]);
  uint2* yrow = (uint2*)(y + (size_t)row * 512);
  yrow[l * 2] = p0;
  yrow[l * 2 + 1] = p1;
}

// ---------------- k4: GEMM2 + bias -> out (fp32), 128x64 tiles ----------------
__global__ __launch_bounds__(256, 2) void gemm2_kernel(
    const unsigned short* __restrict__ yb,   // [8192][512]
    const unsigned short* __restrict__ w2b,  // [512][512]
    const float* __restrict__ b2, float* __restrict__ out) {
  __shared__ __align__(16) unsigned short As[128 * 64];
  __shared__ __align__(16) unsigned short Bs[64 * 64];
  const int tid = threadIdx.x;
  const int w = tid >> 6, l = tid & 63;
  const int bm = blockIdx.x & 63, bn = blockIdx.x >> 6;  // bn in [0,8)
  const int wm = w & 1, wn = w >> 1;
  const int quad = l >> 4, lc = l & 15, lc7 = lc & 7;
  const int r8 = l >> 3, c8 = (l & 7) ^ r8;

  f32x4 acc[4][2] = {};
  const unsigned short* ga = yb + (size_t)(bm * 128 + w * 32 + r8) * 512 + c8 * 8;
  const unsigned short* gb = w2b + (size_t)(bn * 64 + w * 16 + r8) * 512 + c8 * 8;

  for (int kt = 0; kt < 512; kt += 64) {
#pragma unroll
    for (int i = 0; i < 4; ++i)
      gl_lds16(ga + i * 8 * 512 + kt, As + (w * 4 + i) * 512);
#pragma unroll
    for (int i = 0; i < 2; ++i)
      gl_lds16(gb + i * 8 * 512 + kt, Bs + (w * 2 + i) * 512);
    __syncthreads();
#pragma unroll
    for (int kk = 0; kk < 2; ++kk) {
      short8 af[4], bf[2];
#pragma unroll
      for (int mt = 0; mt < 4; ++mt)
        af[mt] = *(const short8*)(As + (wm * 64 + mt * 16 + lc) * 64 +
                                  (((kk * 4 + quad) ^ lc7) * 8));
#pragma unroll
      for (int nt = 0; nt < 2; ++nt)
        bf[nt] = *(const short8*)(Bs + (wn * 32 + nt * 16 + lc) * 64 +
                                  (((kk * 4 + quad) ^ lc7) * 8));
#pragma unroll
      for (int mt = 0; mt < 4; ++mt)
#pragma unroll
        for (int nt = 0; nt < 2; ++nt)
          acc[mt][nt] = __builtin_amdgcn_mfma_f32_16x16x32_bf16(af[mt], bf[nt], acc[mt][nt], 0, 0, 0);
    }
    __syncthreads();
  }

#pragma unroll
  for (int nt = 0; nt < 2; ++nt) {
    const int n = bn * 64 + wn * 32 + nt * 16 + lc;
    const float bias = b2[n];
#pragma unroll
    for (int mt = 0; mt < 4; ++mt) {
      const int m0 = bm * 128 + wm * 64 + mt * 16 + quad * 4;
#pragma unroll
      for (int r = 0; r < 4; ++r)
        out[(size_t)(m0 + r) * 512 + n] = acc[mt][nt][r] + bias;
    }
  }
}

extern "C" void kernel_launch(void* const* d_in, const int* in_sizes, int n_in,
                              void* d_out, int out_size, void* d_ws, size_t ws_size,
                              hipStream_t stream) {
  const float* x = (const float*)d_in[0];
  const float* W1 = (const float*)d_in[1];
  const float* b1 = (const float*)d_in[2];
  const float* lng = (const float*)d_in[3];
  const float* lnb = (const float*)d_in[4];
  const float* W2 = (const float*)d_in[5];
  const float* b2 = (const float*)d_in[6];
  float* out = (float*)d_out;
  char* ws = (char*)d_ws;

  unsigned short* xb  = (unsigned short*)(ws);
  unsigned short* w1b = (unsigned short*)(ws + 8388608);
  unsigned short* w2b = (unsigned short*)(ws + 10485760);
  unsigned short* h   = (unsigned short*)(ws + 11010048);
  unsigned short* vt  = (unsigned short*)(ws + 44564480);
  float* o            = (float*)(ws + 52953088);
  unsigned short* yb  = (unsigned short*)(ws + 69730304);
  float* o1           = (float*)(ws);  // reuses xb (dead after gemm1): 4*1024*512*4B = 8 MB

  convert_kernel<<<5376, 256, 0, stream>>>(x, W1, W2, xb, w1b, w2b);
  gemm1_kernel<<<1024, 256, 0, stream>>>(xb, w1b, b1, h, vt);
  attn_kernel<<<1024, 256, 0, stream>>>(h, vt, o, o1);
  ln_gate_kernel<<<2048, 256, 0, stream>>>(o, o1, h, lng, lnb, yb);
  gemm2_kernel<<<512, 256, 0, stream>>>(yb, w2b, b2, out);
}

// Round 5
// 154.979 us; speedup vs baseline: 1.1645x; 1.1196x over previous
//
#include <hip/hip_runtime.h>
#include <hip/hip_bf16.h>
#include <cstdint>

// HSTU fused block on MI355X.
//   k0: convert x,W1,W2 fp32->bf16
//   k1: h = silu(x@W1^T+b1) -> gate/q/k into h[8192][2048] (q pre-scaled 0.125), v -> Vt[b,h,d,t]
//       V columns stored PERMUTED within each 32-t chunk (pos quad*8+j <-> t=(j>>2)*16+quad*4+(j&3))
//       so attn's PV A-fragment is lane-local (P stays in registers, no Ps LDS buffer).
//   k2: causal silu-attention (Q-tile 64, K-tile 128, LPT, R1 scheduling) + TRUE double-buffer:
//       Ks0/Ks1/Vs0/Vs1 are SEPARATE arrays (static alias disambiguation) so the prefetch
//       global_load_lds for tile ti+1 stays in flight across tile ti's ds_reads; the only
//       vmcnt(0) is at the end-of-tile barrier (1 barrier/tile vs R1's 2).
//   k3: y = (layernorm(o)*g+b) * gate  (bf16)
//   k4: out = y@W2^T + b2 (fp32)
// All MFMA staging tiles use XOR swizzle: LDS chunk c of row r holds global chunk c^(r&7)
// (gl_lds16 writes lane*16B at fixed LDS offset; we permute the *global* source per lane).

typedef __attribute__((ext_vector_type(8))) short short8;
typedef __attribute__((ext_vector_type(4))) float f32x4;

__device__ __forceinline__ unsigned short f2bf(float f) {
  union { float f; unsigned u; } v; v.f = f;
  unsigned r = v.u + 0x7FFFu + ((v.u >> 16) & 1u);
  return (unsigned short)(r >> 16);
}
__device__ __forceinline__ float bf2f(unsigned short h) {
  union { unsigned u; float f; } v; v.u = ((unsigned)h) << 16; return v.f;
}
__device__ __forceinline__ float fast_rcp(float x) {
#if __has_builtin(__builtin_amdgcn_rcpf)
  return __builtin_amdgcn_rcpf(x);
#else
  return 1.0f / x;
#endif
}
__device__ __forceinline__ float fast_exp2(float x) {
#if __has_builtin(__builtin_amdgcn_exp2f)
  return __builtin_amdgcn_exp2f(x);
#else
  return exp2f(x);
#endif
}
// silu without the IEEE-div sequence: x * rcp(1 + 2^(-x*log2e))
__device__ __forceinline__ float silu_f(float x) {
  return x * fast_rcp(1.0f + fast_exp2(-1.442695041f * x));
}
__device__ __forceinline__ unsigned pk2(float lo, float hi) {
  union { __hip_bfloat162 b; unsigned u; } cv;
  cv.b = __float22bfloat162_rn(make_float2(lo, hi));
  return cv.u;
}
__device__ __forceinline__ void gl_lds16(const void* g, void* l) {
  __builtin_amdgcn_global_load_lds(
      (const __attribute__((address_space(1))) void*)g,
      (__attribute__((address_space(3))) void*)l, 16, 0, 0);
}

// ---------------- k0: fp32 -> bf16 convert ----------------
__global__ void convert_kernel(const float* __restrict__ x, const float* __restrict__ w1,
                               const float* __restrict__ w2,
                               unsigned short* __restrict__ xb, unsigned short* __restrict__ w1b,
                               unsigned short* __restrict__ w2b) {
  int i = blockIdx.x * 256 + threadIdx.x;  // one float4 per thread
  const float* s; unsigned short* d;
  if (i < 1048576) { s = x; d = xb; }
  else if (i < 1048576 + 262144) { i -= 1048576; s = w1; d = w1b; }
  else { i -= (1048576 + 262144); if (i >= 65536) return; s = w2; d = w2b; }
  float4 f = ((const float4*)s)[i];
  uint2 o; o.x = pk2(f.x, f.y); o.y = pk2(f.z, f.w);
  ((uint2*)d)[i] = o;
}

// ---------------- k1: GEMM1 + bias + silu -> h (gate/q/k) and vt (v transposed) ----------------
__global__ __launch_bounds__(256, 2) void gemm1_kernel(
    const unsigned short* __restrict__ xb,   // [8192][512]
    const unsigned short* __restrict__ w1b,  // [2048][512]
    const float* __restrict__ b1,            // [2048]
    unsigned short* __restrict__ h,          // [8192][2048] (cols 1536+ unused)
    unsigned short* __restrict__ vt)         // [32*64][2048]  ((b*8+hh)*64+d, pos)
{
  __shared__ __align__(16) unsigned short smem[16896];  // As|Bs (16384) then T[128][132]
  unsigned short* As = smem;          // [128][64] swizzled
  unsigned short* Bs = smem + 8192;
  const int tid = threadIdx.x;
  const int w = tid >> 6, l = tid & 63;
  const int bm = blockIdx.x & 63, bn = blockIdx.x >> 6;
  const int wm = w & 1, wn = w >> 1;
  const int quad = l >> 4, lc = l & 15, lc7 = lc & 7;
  const int r8 = l >> 3, c8 = (l & 7) ^ r8;  // swizzled global chunk

  f32x4 acc[4][4] = {};
  const unsigned short* ga = xb + (size_t)(bm * 128 + w * 32 + r8) * 512 + c8 * 8;
  const unsigned short* gb = w1b + (size_t)(bn * 128 + w * 32 + r8) * 512 + c8 * 8;

  for (int kt = 0; kt < 512; kt += 64) {
#pragma unroll
    for (int i = 0; i < 4; ++i) {
      gl_lds16(ga + i * 8 * 512 + kt, As + (w * 4 + i) * 512);
      gl_lds16(gb + i * 8 * 512 + kt, Bs + (w * 4 + i) * 512);
    }
    __syncthreads();
#pragma unroll
    for (int kk = 0; kk < 2; ++kk) {
      short8 af[4], bf[4];
#pragma unroll
      for (int mt = 0; mt < 4; ++mt)
        af[mt] = *(const short8*)(As + (wm * 64 + mt * 16 + lc) * 64 +
                                  (((kk * 4 + quad) ^ lc7) * 8));
#pragma unroll
      for (int nt = 0; nt < 4; ++nt)
        bf[nt] = *(const short8*)(Bs + (wn * 64 + nt * 16 + lc) * 64 +
                                  (((kk * 4 + quad) ^ lc7) * 8));
#pragma unroll
      for (int mt = 0; mt < 4; ++mt)
#pragma unroll
        for (int nt = 0; nt < 4; ++nt)
          acc[mt][nt] = __builtin_amdgcn_mfma_f32_16x16x32_bf16(af[mt], bf[nt], acc[mt][nt], 0, 0, 0);
    }
    __syncthreads();
  }

  // epilogue: repack C-tile through LDS T, then 256B-coalesced global stores
  unsigned short* T = smem;  // [128][132]
  const int sec = bn >> 2;   // 0 gate, 1 q, 2 k, 3 v (uniform per block)
  if (sec == 3) {
    // T[d_local][s_local]: regs hold 4 consecutive s at fixed n=d -> b64 LDS writes
#pragma unroll
    for (int nt = 0; nt < 4; ++nt) {
      const int nl = wn * 64 + nt * 16 + lc;
      const float bias = b1[bn * 128 + nl];
#pragma unroll
      for (int mt = 0; mt < 4; ++mt) {
        const int sl = wm * 64 + mt * 16 + quad * 4;
        uint2 pk;
        pk.x = pk2(silu_f(acc[mt][nt][0] + bias), silu_f(acc[mt][nt][1] + bias));
        pk.y = pk2(silu_f(acc[mt][nt][2] + bias), silu_f(acc[mt][nt][3] + bias));
        *(uint2*)(T + nl * 132 + sl) = pk;
      }
    }
  } else {
    const float osc = (sec == 1) ? 0.125f : 1.0f;  // fold attention scale into q
#pragma unroll
    for (int nt = 0; nt < 4; ++nt) {
      const int nl = wn * 64 + nt * 16 + lc;
      const float bias = b1[bn * 128 + nl];
#pragma unroll
      for (int mt = 0; mt < 4; ++mt) {
        const int sl = wm * 64 + mt * 16 + quad * 4;
#pragma unroll
        for (int r = 0; r < 4; ++r)
          T[(sl + r) * 132 + nl] = f2bf(silu_f(acc[mt][nt][r] + bias) * osc);
      }
    }
  }
  __syncthreads();
  const int rrow = tid >> 4, rcol = (tid & 15) * 8;
  if (sec == 3) {
    // store V with per-32-chunk position permutation: pos quad*8+j <-> t=(j>>2)*16+quad*4+(j&3)
    const int bq = bm >> 4, sbase = (bm & 15) * 128;
    const int lcq = tid & 15;
    const int t0 = ((lcq >> 2) * 32) + ((lcq & 3) * 4);  // ksl*32 + quad*4
#pragma unroll
    for (int p = 0; p < 8; ++p) {
      const int row = p * 16 + rrow;
      const int n = bn * 128 + row, hh = (n >> 6) & 7, d = n & 63;
      uint2 a = *(const uint2*)(T + row * 132 + t0);
      uint2 bb = *(const uint2*)(T + row * 132 + t0 + 16);
      uint4 st; st.x = a.x; st.y = a.y; st.z = bb.x; st.w = bb.y;
      *(uint4*)(vt + (size_t)((bq * 8 + hh) * 64 + d) * 2048 + sbase + rcol) = st;
    }
  } else {
#pragma unroll
    for (int p = 0; p < 8; ++p) {
      const int row = p * 16 + rrow;
      *(short8*)(h + (size_t)(bm * 128 + row) * 2048 + bn * 128 + rcol) =
          *(const short8*)(T + row * 132 + rcol);
    }
  }
}

// ---------------- k2: causal silu-attention (Q-tile 64, K-tile 128, LPT, dbuf) ----------------
// Per wave: q rows [w*16, w*16+16), all 128 t. P stays in registers.
// Statically distinct Ks0/Ks1/Vs0/Vs1 let prefetch(ti+1) fly over compute(ti)'s ds_reads.
__global__ __launch_bounds__(256, 2) void attn_kernel(
    const unsigned short* __restrict__ h,   // q @ +512 (pre-scaled), k @ +1024
    const unsigned short* __restrict__ vt,  // [32*64][2048] position-permuted
    float* __restrict__ o)                  // [8192][512]
{
  __shared__ __align__(16) unsigned short Qs[64 * 64];    // 8KB
  __shared__ __align__(16) unsigned short Ks0[128 * 64];  // 16KB swizzled
  __shared__ __align__(16) unsigned short Vs0[64 * 128];  // 16KB [d][pos] swizzled
  __shared__ __align__(16) unsigned short Ks1[128 * 64];  // 16KB
  __shared__ __align__(16) unsigned short Vs1[64 * 128];  // 16KB
  const int tid = threadIdx.x;
  const int w = tid >> 6, l = tid & 63;
  const int bh = blockIdx.x & 31;
  const int qi = 31 - (blockIdx.x >> 5);  // LPT: longest first
  const int b = bh >> 3, hh = bh & 7;
  const int quad = l >> 4, lc = l & 15, lc7 = lc & 7;
  const int r8 = l >> 3, c8 = (l & 7) ^ r8;
  const int q0 = qi * 64;
  const int nk = (qi >> 1) + 1;

  const unsigned short* kg =
      h + (size_t)(b * 2048 + w * 32 + r8) * 2048 + 1024 + hh * 64 + c8 * 8;
  const int vrow = l >> 4, vcol = l & 15;
  const unsigned short* vgE =
      vt + (size_t)(bh * 64 + w * 16 + vrow) * 2048 + ((vcol ^ vrow) * 8);
  const unsigned short* vgO =
      vt + (size_t)(bh * 64 + w * 16 + vrow) * 2048 + ((vcol ^ vrow ^ 4) * 8);

  f32x4 oacc[4] = {};
  short8 qf[2];

  auto stageKV = [&](int ti, unsigned short* Kd, unsigned short* Vd) {
    const int toff = ti * 128;
#pragma unroll
    for (int i = 0; i < 4; ++i) {
      gl_lds16(kg + (size_t)(toff + i * 8) * 2048, Kd + (w * 4 + i) * 512);
      const unsigned short* vsrc = ((i & 1) ? vgO : vgE) + (size_t)(i * 4) * 2048 + toff;
      gl_lds16(vsrc, Vd + (w * 4 + i) * 512);
    }
  };
  auto computeTile = [&](const unsigned short* Kb, const unsigned short* Vb, bool dg,
                         int toff) {
    // Sc^T = K Q^T : lane holds C[t = mt*16 + quad*4 + r][q = w*16 + lc]
    f32x4 sc[8] = {};
#pragma unroll
    for (int kk = 0; kk < 2; ++kk)
#pragma unroll
      for (int mt = 0; mt < 8; ++mt) {
        short8 kf = *(const short8*)(Kb + (mt * 16 + lc) * 64 +
                                     (((kk * 4 + quad) ^ lc7) * 8));
        sc[mt] = __builtin_amdgcn_mfma_f32_16x16x32_bf16(kf, qf[kk], sc[mt], 0, 0, 0);
      }
    // silu (+causal mask on diagonal tile) in-register, then PV.
    // PV A-frag position quad*8+j <-> t = ks*32 + (j>>2)*16 + quad*4 + (j&3)
    // == lane's own sc[2ks + (j>>2)][j&3]; V stored position-permuted to match.
    if (!dg) {
#pragma unroll
      for (int ks = 0; ks < 4; ++ks) {
        union { short8 s; unsigned u[4]; } pf;
        pf.u[0] = pk2(silu_f(sc[2 * ks][0]), silu_f(sc[2 * ks][1]));
        pf.u[1] = pk2(silu_f(sc[2 * ks][2]), silu_f(sc[2 * ks][3]));
        pf.u[2] = pk2(silu_f(sc[2 * ks + 1][0]), silu_f(sc[2 * ks + 1][1]));
        pf.u[3] = pk2(silu_f(sc[2 * ks + 1][2]), silu_f(sc[2 * ks + 1][3]));
#pragma unroll
        for (int nt = 0; nt < 4; ++nt) {
          short8 vf = *(const short8*)(Vb + (nt * 16 + lc) * 128 +
                                       (((ks * 4 + quad) ^ lc7) * 8));
          oacc[nt] = __builtin_amdgcn_mfma_f32_16x16x32_bf16(pf.s, vf, oacc[nt], 0, 0, 0);
        }
      }
    } else {
      const int qrow = q0 + w * 16 + lc;
#pragma unroll
      for (int ks = 0; ks < 4; ++ks) {
        float v[8];
#pragma unroll
        for (int g = 0; g < 2; ++g) {
          const int tb = toff + (2 * ks + g) * 16 + quad * 4;
#pragma unroll
          for (int r = 0; r < 4; ++r) {
            float s = silu_f(sc[2 * ks + g][r]);
            v[g * 4 + r] = (tb + r <= qrow) ? s : 0.0f;
          }
        }
        union { short8 s; unsigned u[4]; } pf;
        pf.u[0] = pk2(v[0], v[1]);
        pf.u[1] = pk2(v[2], v[3]);
        pf.u[2] = pk2(v[4], v[5]);
        pf.u[3] = pk2(v[6], v[7]);
#pragma unroll
        for (int nt = 0; nt < 4; ++nt) {
          short8 vf = *(const short8*)(Vb + (nt * 16 + lc) * 128 +
                                       (((ks * 4 + quad) ^ lc7) * 8));
          oacc[nt] = __builtin_amdgcn_mfma_f32_16x16x32_bf16(pf.s, vf, oacc[nt], 0, 0, 0);
        }
      }
    }
  };

  // prologue: Q -> Qs (dedicated buffer), tile 0 -> buf0
  {
    const unsigned short* qg =
        h + (size_t)(b * 2048 + q0 + w * 16 + r8) * 2048 + 512 + hh * 64 + c8 * 8;
#pragma unroll
    for (int i = 0; i < 2; ++i)
      gl_lds16(qg + (size_t)i * 8 * 2048, Qs + (w * 2 + i) * 512);
  }
  stageKV(0, Ks0, Vs0);
  __syncthreads();
#pragma unroll
  for (int kk = 0; kk < 2; ++kk)
    qf[kk] = *(const short8*)(Qs + (w * 16 + lc) * 64 + (((kk * 4 + quad) ^ lc7) * 8));

  // pipelined main loop: issue stage(ti+1 -> other buf), compute(ti), barrier (drains vmcnt)
  for (int ti = 0; ti < nk; ti += 2) {
    if (ti + 1 < nk) stageKV(ti + 1, Ks1, Vs1);
    computeTile(Ks0, Vs0, ti == nk - 1, ti * 128);
    __syncthreads();
    if (ti + 1 < nk) {
      if (ti + 2 < nk) stageKV(ti + 2, Ks0, Vs0);
      computeTile(Ks1, Vs1, ti + 1 == nk - 1, (ti + 1) * 128);
      __syncthreads();
    }
  }

  float* og = o + (size_t)(b * 2048 + q0 + w * 16) * 512 + hh * 64;
#pragma unroll
  for (int nt = 0; nt < 4; ++nt)
#pragma unroll
    for (int r = 0; r < 4; ++r)
      og[(quad * 4 + r) * 512 + nt * 16 + lc] = oacc[nt][r];
}

// ---------------- k3: layernorm * gate -> y (bf16) ----------------
__global__ __launch_bounds__(256) void ln_gate_kernel(
    const float* __restrict__ o, const unsigned short* __restrict__ h,
    const float* __restrict__ lng, const float* __restrict__ lnb,
    unsigned short* __restrict__ y) {
  const int row = blockIdx.x * 4 + (threadIdx.x >> 6);
  const int l = threadIdx.x & 63;
  const float4* orow = (const float4*)(o + (size_t)row * 512);
  float4 a = orow[l * 2], c = orow[l * 2 + 1];
  float s0 = a.x + a.y + a.z + a.w + c.x + c.y + c.z + c.w;
#pragma unroll
  for (int off = 32; off > 0; off >>= 1) s0 += __shfl_xor(s0, off);
  const float mean = s0 * (1.0f / 512.0f);
  float dx[8] = {a.x - mean, a.y - mean, a.z - mean, a.w - mean,
                 c.x - mean, c.y - mean, c.z - mean, c.w - mean};
  float sq = 0.f;
#pragma unroll
  for (int j = 0; j < 8; ++j) sq += dx[j] * dx[j];
#pragma unroll
  for (int off = 32; off > 0; off >>= 1) sq += __shfl_xor(sq, off);
  const float inv = rsqrtf(sq * (1.0f / 512.0f) + 1e-5f);
  const float4* g4 = (const float4*)lng;
  const float4* b4 = (const float4*)lnb;
  float4 g0 = g4[l * 2], g1 = g4[l * 2 + 1], bb0 = b4[l * 2], bb1 = b4[l * 2 + 1];
  const unsigned short* grow = h + (size_t)row * 2048;  // gate = cols [0,512)
  ushort4 gr0 = *(const ushort4*)(grow + l * 8);
  ushort4 gr1 = *(const ushort4*)(grow + l * 8 + 4);
  float gg[8] = {g0.x, g0.y, g0.z, g0.w, g1.x, g1.y, g1.z, g1.w};
  float bbv[8] = {bb0.x, bb0.y, bb0.z, bb0.w, bb1.x, bb1.y, bb1.z, bb1.w};
  float gv[8] = {bf2f(gr0.x), bf2f(gr0.y), bf2f(gr0.z), bf2f(gr0.w),
                 bf2f(gr1.x), bf2f(gr1.y), bf2f(gr1.z), bf2f(gr1.w)};
  float r[8];
#pragma unroll
  for (int j = 0; j < 8; ++j) r[j] = (dx[j] * inv * gg[j] + bbv[j]) * gv[j];
  uint2 p0, p1;
  p0.x = pk2(r[0], r[1]); p0.y = pk2(r[2], r[3]);
  p1.x = pk2(r[4], r[5]); p1.y = pk2(r[6], r[7]);
  uint2* yrow = (uint2*)(y + (size_t)row * 512);
  yrow[l * 2] = p0;
  yrow[l * 2 + 1] = p1;
}

// ---------------- k4: GEMM2 + bias -> out (fp32) ----------------
__global__ __launch_bounds__(256, 2) void gemm2_kernel(
    const unsigned short* __restrict__ yb,   // [8192][512]
    const unsigned short* __restrict__ w2b,  // [512][512]
    const float* __restrict__ b2, float* __restrict__ out) {
  __shared__ __align__(16) unsigned short As[128 * 64];
  __shared__ __align__(16) unsigned short Bs[128 * 64];
  const int tid = threadIdx.x;
  const int w = tid >> 6, l = tid & 63;
  const int bm = blockIdx.x & 63, bn = blockIdx.x >> 6;
  const int wm = w & 1, wn = w >> 1;
  const int quad = l >> 4, lc = l & 15, lc7 = lc & 7;
  const int r8 = l >> 3, c8 = (l & 7) ^ r8;

  f32x4 acc[4][4] = {};
  const unsigned short* ga = yb + (size_t)(bm * 128 + w * 32 + r8) * 512 + c8 * 8;
  const unsigned short* gb = w2b + (size_t)(bn * 128 + w * 32 + r8) * 512 + c8 * 8;

  for (int kt = 0; kt < 512; kt += 64) {
#pragma unroll
    for (int i = 0; i < 4; ++i) {
      gl_lds16(ga + i * 8 * 512 + kt, As + (w * 4 + i) * 512);
      gl_lds16(gb + i * 8 * 512 + kt, Bs + (w * 4 + i) * 512);
    }
    __syncthreads();
#pragma unroll
    for (int kk = 0; kk < 2; ++kk) {
      short8 af[4], bf[4];
#pragma unroll
      for (int mt = 0; mt < 4; ++mt)
        af[mt] = *(const short8*)(As + (wm * 64 + mt * 16 + lc) * 64 +
                                  (((kk * 4 + quad) ^ lc7) * 8));
#pragma unroll
      for (int nt = 0; nt < 4; ++nt)
        bf[nt] = *(const short8*)(Bs + (wn * 64 + nt * 16 + lc) * 64 +
                                  (((kk * 4 + quad) ^ lc7) * 8));
#pragma unroll
      for (int mt = 0; mt < 4; ++mt)
#pragma unroll
        for (int nt = 0; nt < 4; ++nt)
          acc[mt][nt] = __builtin_amdgcn_mfma_f32_16x16x32_bf16(af[mt], bf[nt], acc[mt][nt], 0, 0, 0);
    }
    __syncthreads();
  }

#pragma unroll
  for (int nt = 0; nt < 4; ++nt) {
    const int n = bn * 128 + wn * 64 + nt * 16 + lc;
    const float bias = b2[n];
#pragma unroll
    for (int mt = 0; mt < 4; ++mt) {
      const int m0 = bm * 128 + wm * 64 + mt * 16 + quad * 4;
#pragma unroll
      for (int r = 0; r < 4; ++r)
        out[(size_t)(m0 + r) * 512 + n] = acc[mt][nt][r] + bias;
    }
  }
}

extern "C" void kernel_launch(void* const* d_in, const int* in_sizes, int n_in,
                              void* d_out, int out_size, void* d_ws, size_t ws_size,
                              hipStream_t stream) {
  const float* x = (const float*)d_in[0];
  const float* W1 = (const float*)d_in[1];
  const float* b1 = (const float*)d_in[2];
  const float* lng = (const float*)d_in[3];
  const float* lnb = (const float*)d_in[4];
  const float* W2 = (const float*)d_in[5];
  const float* b2 = (const float*)d_in[6];
  float* out = (float*)d_out;
  char* ws = (char*)d_ws;

  unsigned short* xb  = (unsigned short*)(ws);
  unsigned short* w1b = (unsigned short*)(ws + 8388608);
  unsigned short* w2b = (unsigned short*)(ws + 10485760);
  unsigned short* h   = (unsigned short*)(ws + 11010048);
  unsigned short* vt  = (unsigned short*)(ws + 44564480);
  float* o            = (float*)(ws + 52953088);
  unsigned short* yb  = (unsigned short*)(ws + 69730304);

  convert_kernel<<<5376, 256, 0, stream>>>(x, W1, W2, xb, w1b, w2b);
  gemm1_kernel<<<1024, 256, 0, stream>>>(xb, w1b, b1, h, vt);
  attn_kernel<<<1024, 256, 0, stream>>>(h, vt, o);
  ln_gate_kernel<<<2048, 256, 0, stream>>>(o, h, lng, lnb, yb);
  gemm2_kernel<<<256, 256, 0, stream>>>(yb, w2b, b2, out);
}